// Round 6
// baseline (277.152 us; speedup 1.0000x reference)
//
#include <hip/hip_runtime.h>

// PathGNNLayers: per-edge MLP + scatter-max GNN layer.
//   x:[N,32] f32, edge_index:[2,E] int32, edge_attr:[E,32] f32
//   W1:[96,64], b1:[64], W2:[64,32], b2:[32]
//   out[n] = max( x[n, -32:], max_{e: col[e]==n} MLP(x[row_e], x[col_e], ea[e]) )
//
// R6: exact-CSR aggregation (count -> scan -> scatter) replaces CAP buckets;
// kills the 47MB scattered-write amplification. Gather uses shfl-broadcast
// edge ids + 4 independent max chains for load pipelining. prep fuses
// zeroing + x->bf16 + weight shuffle.

constexpr int XD   = 32;
constexpr int HID  = 64;
constexpr int OUTD = 32;
constexpr int BM   = 128;   // edges per block (MFMA kernel)
constexpr int ASTR = 104;   // A LDS stride in bf16 units
constexpr int HSTR = 72;    // H LDS stride in bf16 units
constexpr int VSTR = 40;    // V staging stride in bf16 units

typedef __attribute__((ext_vector_type(8)))  short    short8;
typedef __attribute__((ext_vector_type(4)))  float    f32x4;
typedef __attribute__((ext_vector_type(4)))  float    floatx4;
typedef __attribute__((ext_vector_type(4)))  unsigned u32x4;

static __device__ __forceinline__ unsigned f2bf(float f) {
    union { float f; unsigned u; } x; x.f = f;
    unsigned r = x.u + 0x7fff + ((x.u >> 16) & 1);   // RNE; finite inputs
    return r >> 16;
}

// ---- prep: degree=0, x->bf16 table, W1/W2 -> bf16 MFMA B-fragment order ----
__global__ __launch_bounds__(256) void prep(
    const float* __restrict__ x, unsigned* __restrict__ xbf,
    const float* __restrict__ W1, const float* __restrict__ W2,
    unsigned* __restrict__ w1s, unsigned* __restrict__ w2s,
    unsigned* __restrict__ degree, int n_nodes, int total8)
{
    const int i = blockIdx.x * 256 + threadIdx.x;

    if (i < total8) {                      // x (f32) -> xbf (bf16), 8 floats/thread
        const float4* src = reinterpret_cast<const float4*>(x) + (size_t)i * 2;
        float4 a = src[0], b = src[1];
        uint4 o;
        o.x = f2bf(a.x) | (f2bf(a.y) << 16);
        o.y = f2bf(a.z) | (f2bf(a.w) << 16);
        o.z = f2bf(b.x) | (f2bf(b.y) << 16);
        o.w = f2bf(b.z) | (f2bf(b.w) << 16);
        reinterpret_cast<uint4*>(xbf)[i] = o;
    }
    if (i < n_nodes) degree[i] = 0u;

    // B-frag for tile (nt,ks): lane l holds B[k=ks*32+(l>>4)*8+j][col=nt*16+(l&15)]
    if (i < 768) {                         // W1: 4 nt x 3 ks x 64 lanes
        const int ti = i >> 6, lane = i & 63;
        const int nt = ti / 3, ks = ti % 3;
        const int col = nt * 16 + (lane & 15);
        const int k0  = ks * 32 + ((lane >> 4) << 3);
        unsigned o[4];
#pragma unroll
        for (int p = 0; p < 4; ++p)
            o[p] = f2bf(W1[(k0 + 2 * p) * HID + col]) |
                   (f2bf(W1[(k0 + 2 * p + 1) * HID + col]) << 16);
        reinterpret_cast<uint4*>(w1s)[i] = make_uint4(o[0], o[1], o[2], o[3]);
    } else if (i < 1024) {                 // W2: 2 nt x 2 ks x 64 lanes
        const int tt = i - 768;
        const int ti = tt >> 6, lane = tt & 63;
        const int nt = ti >> 1, ks = ti & 1;
        const int col = nt * 16 + (lane & 15);
        const int k0  = ks * 32 + ((lane >> 4) << 3);
        unsigned o[4];
#pragma unroll
        for (int p = 0; p < 4; ++p)
            o[p] = f2bf(W2[(k0 + 2 * p) * OUTD + col]) |
                   (f2bf(W2[(k0 + 2 * p + 1) * OUTD + col]) << 16);
        reinterpret_cast<uint4*>(w2s)[tt] = make_uint4(o[0], o[1], o[2], o[3]);
    }
}

__global__ __launch_bounds__(256) void count_deg(
    const int* __restrict__ ei, unsigned* __restrict__ degree, int n_edges)
{
    int e = blockIdx.x * 256 + threadIdx.x;
    if (e < n_edges) atomicAdd(&degree[ei[n_edges + e]], 1u);
}

// single-block exclusive scan: start[0..N] (start[N]=E), cursor = start copy
__global__ __launch_bounds__(1024) void prefix_scan(
    const unsigned* __restrict__ degree,
    unsigned* __restrict__ start, unsigned* __restrict__ cursor, int n_nodes)
{
    __shared__ unsigned sums[1024];
    const int t = threadIdx.x;
    const int chunk = (n_nodes + 1023) / 1024;
    const int lo = t * chunk;
    const int hi = min(lo + chunk, n_nodes);

    unsigned s = 0;
    for (int i = lo; i < hi; ++i) s += degree[i];
    sums[t] = s;
    __syncthreads();
#pragma unroll
    for (int off = 1; off < 1024; off <<= 1) {
        unsigned val = (t >= off) ? sums[t - off] : 0u;
        __syncthreads();
        sums[t] += val;
        __syncthreads();
    }
    unsigned base = (t == 0) ? 0u : sums[t - 1];
    for (int i = lo; i < hi; ++i) {
        start[i]  = base;
        cursor[i] = base;
        base += degree[i];
    }
    if (t == 1023) start[n_nodes] = sums[1023];
}

__global__ __launch_bounds__(256) void scatter_csr(
    const int* __restrict__ ei, unsigned* __restrict__ cursor,
    unsigned* __restrict__ csr, int n_edges)
{
    int e = blockIdx.x * 256 + threadIdx.x;
    if (e >= n_edges) return;
    const int col = ei[n_edges + e];
    const unsigned pos = atomicAdd(&cursor[col], 1u);
    csr[pos] = (unsigned)e;
}

// ---- per-128-edge-block MFMA MLP ----
__global__ __launch_bounds__(256) void edge_mlp_mfma(
    const unsigned* __restrict__ xbf,   // [N][16] u32 = [N][32] bf16
    const int*      __restrict__ ei,
    const float*    __restrict__ ea,
    const unsigned* __restrict__ w1s,   // [12][64] x 16B frags
    const unsigned* __restrict__ w2s,   // [4][64] x 16B frags
    const float*    __restrict__ b1,
    const float*    __restrict__ b2,
    unsigned*       __restrict__ v,     // [E][16] u32 = [E][32] bf16
    int n_edges)
{
    __shared__ alignas(16) unsigned short Albs[BM * ASTR];
    __shared__ alignas(16) unsigned short Hlds[BM * HSTR];

    const int t    = threadIdx.x;
    const int lane = t & 63;
    const int wave = t >> 6;
    const int base = blockIdx.x * BM;

    // stage A[:, 0:64]: gather 2 endpoint rows per edge (thread = (edge, side))
    {
        const int m    = t & 127;
        const int side = t >> 7;
        int e = base + m; if (e >= n_edges) e = n_edges - 1;
        const int id = ei[side * n_edges + e];
        const uint4* src = reinterpret_cast<const uint4*>(xbf + (size_t)id * 16);
#pragma unroll
        for (int q = 0; q < 4; ++q)
            *reinterpret_cast<uint4*>(&Albs[m * ASTR + side * 32 + q * 8]) = src[q];
    }
    // stage A[:, 64:96]: ea f32->bf16, coalesced non-temporal stream
    {
#pragma unroll
        for (int i = 0; i < 4; ++i) {
            const int f = t + i * 256;
            const int m = f >> 3;
            const int c = (f & 7) * 4;
            int e = base + m; if (e >= n_edges) e = n_edges - 1;
            const floatx4 d = __builtin_nontemporal_load(
                reinterpret_cast<const floatx4*>(ea + (size_t)e * 32 + c));
            uint2 pk;
            pk.x = f2bf(d.x) | (f2bf(d.y) << 16);
            pk.y = f2bf(d.z) | (f2bf(d.w) << 16);
            *reinterpret_cast<uint2*>(&Albs[m * ASTR + 64 + c]) = pk;
        }
    }

    short8 w1f[12];
#pragma unroll
    for (int ti = 0; ti < 12; ++ti)
        w1f[ti] = *reinterpret_cast<const short8*>(w1s + (size_t)(ti * 64 + lane) * 4);
    float bb1[4];
#pragma unroll
    for (int nt = 0; nt < 4; ++nt) bb1[nt] = b1[nt * 16 + (lane & 15)];

    __syncthreads();

    // layer 1: [128x96] @ [96x64]
    f32x4 acc1[2][4];
#pragma unroll
    for (int mi = 0; mi < 2; ++mi)
#pragma unroll
        for (int nt = 0; nt < 4; ++nt) acc1[mi][nt] = (f32x4){0.f, 0.f, 0.f, 0.f};

#pragma unroll
    for (int ks = 0; ks < 3; ++ks) {
#pragma unroll
        for (int mi = 0; mi < 2; ++mi) {
            const int mt = wave * 2 + mi;
            short8 afrag = *reinterpret_cast<const short8*>(
                &Albs[(mt * 16 + (lane & 15)) * ASTR + ks * 32 + ((lane >> 4) << 3)]);
#pragma unroll
            for (int nt = 0; nt < 4; ++nt)
                acc1[mi][nt] = __builtin_amdgcn_mfma_f32_16x16x32_bf16(
                    afrag, w1f[nt * 3 + ks], acc1[mi][nt], 0, 0, 0);
        }
    }

    // bias + ReLU -> H (bf16, LDS). C layout: col=lane&15, row=(lane>>4)*4+r.
#pragma unroll
    for (int mi = 0; mi < 2; ++mi) {
        const int mt = wave * 2 + mi;
#pragma unroll
        for (int nt = 0; nt < 4; ++nt)
#pragma unroll
            for (int r = 0; r < 4; ++r) {
                const float h = fmaxf(acc1[mi][nt][r] + bb1[nt], 0.0f);
                Hlds[(mt * 16 + ((lane >> 4) << 2) + r) * HSTR + nt * 16 + (lane & 15)] =
                    (unsigned short)f2bf(h);
            }
    }

    short8 w2f[4];
#pragma unroll
    for (int ti = 0; ti < 4; ++ti)
        w2f[ti] = *reinterpret_cast<const short8*>(w2s + (size_t)(ti * 64 + lane) * 4);
    float bb2[2];
#pragma unroll
    for (int nt = 0; nt < 2; ++nt) bb2[nt] = b2[nt * 16 + (lane & 15)];

    __syncthreads();

    // layer 2: [128x64] @ [64x32]
    f32x4 acc2[2][2];
#pragma unroll
    for (int mi = 0; mi < 2; ++mi)
#pragma unroll
        for (int nt = 0; nt < 2; ++nt) acc2[mi][nt] = (f32x4){0.f, 0.f, 0.f, 0.f};

#pragma unroll
    for (int ks = 0; ks < 2; ++ks) {
#pragma unroll
        for (int mi = 0; mi < 2; ++mi) {
            const int mt = wave * 2 + mi;
            short8 hfrag = *reinterpret_cast<const short8*>(
                &Hlds[(mt * 16 + (lane & 15)) * HSTR + ks * 32 + ((lane >> 4) << 3)]);
#pragma unroll
            for (int nt = 0; nt < 2; ++nt)
                acc2[mi][nt] = __builtin_amdgcn_mfma_f32_16x16x32_bf16(
                    hfrag, w2f[nt * 2 + ks], acc2[mi][nt], 0, 0, 0);
        }
    }

    // bias, pack V (bf16) via LDS, coalesced store
    unsigned short* Vlds = Albs;
#pragma unroll
    for (int mi = 0; mi < 2; ++mi) {
        const int mt = wave * 2 + mi;
#pragma unroll
        for (int nt = 0; nt < 2; ++nt)
#pragma unroll
            for (int r = 0; r < 4; ++r) {
                const float val = acc2[mi][nt][r] + bb2[nt];
                Vlds[(mt * 16 + ((lane >> 4) << 2) + r) * VSTR + nt * 16 + (lane & 15)] =
                    (unsigned short)f2bf(val);
            }
    }
    __syncthreads();

#pragma unroll
    for (int i = 0; i < 2; ++i) {
        const int f = t + i * 256;
        const int m = f >> 2;
        const int q = f & 3;
        const int e = base + m;
        if (e < n_edges) {
            u32x4 val = *reinterpret_cast<const u32x4*>(&Vlds[m * VSTR + q * 8]);
            __builtin_nontemporal_store(val, reinterpret_cast<u32x4*>(v + (size_t)e * 16) + q);
        }
    }
}

__global__ __launch_bounds__(256) void node_gather_max(
    const float*    __restrict__ x,
    const unsigned* __restrict__ start,  // [N+1]
    const unsigned* __restrict__ csr,    // [E]
    const unsigned short* __restrict__ v,
    float* __restrict__ out, int n_nodes)
{
    const int t = blockIdx.x * 256 + threadIdx.x;
    const int n = t >> 5;          // 32 lanes per node
    const int j = t & 31;
    if (n >= n_nodes) return;

    const unsigned s0 = start[n];
    const int deg = (int)(start[n + 1] - s0);

    const float NEG = __uint_as_float(0xff800000u);
    float m0 = x[(size_t)n * XD + j];   // residual (XD==OUTD)
    float m1 = NEG, m2 = NEG, m3 = NEG;

    int k = 0;
    while (k < deg) {
        const int cnt = min(deg - k, 32);
        unsigned eid = 0;
        if (j < cnt) eid = csr[s0 + k + j];
        int kk = 0;
        for (; kk + 4 <= cnt; kk += 4) {
            const unsigned e0 = __shfl(eid, kk,     32);
            const unsigned e1 = __shfl(eid, kk + 1, 32);
            const unsigned e2 = __shfl(eid, kk + 2, 32);
            const unsigned e3 = __shfl(eid, kk + 3, 32);
            const unsigned u0 = v[(size_t)e0 * OUTD + j];
            const unsigned u1 = v[(size_t)e1 * OUTD + j];
            const unsigned u2 = v[(size_t)e2 * OUTD + j];
            const unsigned u3 = v[(size_t)e3 * OUTD + j];
            m0 = fmaxf(m0, __uint_as_float(u0 << 16));
            m1 = fmaxf(m1, __uint_as_float(u1 << 16));
            m2 = fmaxf(m2, __uint_as_float(u2 << 16));
            m3 = fmaxf(m3, __uint_as_float(u3 << 16));
        }
        for (; kk < cnt; ++kk) {
            const unsigned e0 = __shfl(eid, kk, 32);
            m0 = fmaxf(m0, __uint_as_float((unsigned)v[(size_t)e0 * OUTD + j] << 16));
        }
        k += cnt;
    }
    out[(size_t)n * OUTD + j] = fmaxf(fmaxf(m0, m1), fmaxf(m2, m3));
}

extern "C" void kernel_launch(void* const* d_in, const int* in_sizes, int n_in,
                              void* d_out, int out_size, void* d_ws, size_t ws_size,
                              hipStream_t stream)
{
    const float* x  = (const float*)d_in[0];
    const int*   ei = (const int*)  d_in[1];
    const float* ea = (const float*)d_in[2];
    const float* W1 = (const float*)d_in[3];
    const float* b1 = (const float*)d_in[4];
    const float* W2 = (const float*)d_in[5];
    const float* b2 = (const float*)d_in[6];
    float* out = (float*)d_out;

    const int n_nodes = in_sizes[0] / XD;
    const int n_edges = in_sizes[2] / 32;

    // ws: degree[N] | cursor[N] | start[N+1] | csr[E] | v[E*16 u32] | xbf[N*16 u32] | w1s | w2s
    size_t off = 0;
    unsigned* degree = (unsigned*)((char*)d_ws + off); off += (size_t)n_nodes * 4;
    unsigned* cursor = (unsigned*)((char*)d_ws + off); off += (size_t)n_nodes * 4;
    unsigned* startp = (unsigned*)((char*)d_ws + off); off += (size_t)(n_nodes + 1) * 4;
    off = (off + 15) & ~(size_t)15;
    unsigned* csr    = (unsigned*)((char*)d_ws + off); off += (size_t)n_edges * 4;
    off = (off + 15) & ~(size_t)15;
    unsigned* v      = (unsigned*)((char*)d_ws + off); off += (size_t)n_edges * 16 * 4;
    unsigned* xbf    = (unsigned*)((char*)d_ws + off); off += (size_t)n_nodes * 16 * 4;
    unsigned* w1s    = (unsigned*)((char*)d_ws + off); off += 768 * 16;
    unsigned* w2s    = (unsigned*)((char*)d_ws + off);

    const int total8    = n_nodes * XD / 8;
    const int prep_grid = (max(total8, max(n_nodes, 1024)) + 255) / 256;

    prep<<<prep_grid, 256, 0, stream>>>(x, xbf, W1, W2, w1s, w2s, degree, n_nodes, total8);
    count_deg<<<(n_edges + 255) / 256, 256, 0, stream>>>(ei, degree, n_edges);
    prefix_scan<<<1, 1024, 0, stream>>>(degree, startp, cursor, n_nodes);
    scatter_csr<<<(n_edges + 255) / 256, 256, 0, stream>>>(ei, cursor, csr, n_edges);
    edge_mlp_mfma<<<(n_edges + BM - 1) / BM, 256, 0, stream>>>(
        xbf, ei, ea, w1s, w2s, b1, b2, v, n_edges);
    node_gather_max<<<(n_nodes * 32 + 255) / 256, 256, 0, stream>>>(
        x, startp, csr, (const unsigned short*)v, out, n_nodes);
}

// Round 7
// 175.847 us; speedup vs baseline: 1.5761x; 1.5761x over previous
//
#include <hip/hip_runtime.h>

// PathGNNLayers: per-edge MLP + scatter-max GNN layer.
//   x:[N,32] f32, edge_index:[2,E] int32, edge_attr:[E,32] f32
//   W1:[96,64], b1:[64], W2:[64,32], b2:[32]
//   out[n] = max( x[n, -32:], max_{e: col[e]==n} MLP(x[row_e], x[col_e], ea[e]) )
//
// R7: R6's 110us single-block prefix_scan replaced by a 3-kernel hierarchical
// scan (49-block scan1 / 1-block scan2 over block sums / 196-block scan3).
// count_deg fused into prep (grid-stride over edges).

constexpr int XD   = 32;
constexpr int HID  = 64;
constexpr int OUTD = 32;
constexpr int BM   = 128;   // edges per block (MFMA kernel)
constexpr int ASTR = 104;   // A LDS stride in bf16 units
constexpr int HSTR = 72;    // H LDS stride in bf16 units
constexpr int VSTR = 40;    // V staging stride in bf16 units
constexpr int SCAN_CHUNK = 1024;  // elements per scan1 block (256 thr x 4)

typedef __attribute__((ext_vector_type(8)))  short    short8;
typedef __attribute__((ext_vector_type(4)))  float    f32x4;
typedef __attribute__((ext_vector_type(4)))  float    floatx4;
typedef __attribute__((ext_vector_type(4)))  unsigned u32x4;

static __device__ __forceinline__ unsigned f2bf(float f) {
    union { float f; unsigned u; } x; x.f = f;
    unsigned r = x.u + 0x7fff + ((x.u >> 16) & 1);   // RNE; finite inputs
    return r >> 16;
}

__global__ __launch_bounds__(256) void zero_u32(unsigned* __restrict__ p, int n)
{
    int i = blockIdx.x * 256 + threadIdx.x;
    if (i < n) p[i] = 0u;
}

// ---- prep (grid-stride-free; grid sized for edges): degree count + x->bf16 + weight shuffle
__global__ __launch_bounds__(256) void prep_count(
    const float* __restrict__ x, unsigned* __restrict__ xbf,
    const int* __restrict__ ei,  unsigned* __restrict__ degree,
    const float* __restrict__ W1, const float* __restrict__ W2,
    unsigned* __restrict__ w1s, unsigned* __restrict__ w2s,
    int n_edges, int total8)
{
    const int i = blockIdx.x * 256 + threadIdx.x;

    if (i < n_edges) atomicAdd(&degree[ei[n_edges + i]], 1u);

    if (i < total8) {                      // x (f32) -> xbf (bf16), 8 floats/thread
        const float4* src = reinterpret_cast<const float4*>(x) + (size_t)i * 2;
        float4 a = src[0], b = src[1];
        uint4 o;
        o.x = f2bf(a.x) | (f2bf(a.y) << 16);
        o.y = f2bf(a.z) | (f2bf(a.w) << 16);
        o.z = f2bf(b.x) | (f2bf(b.y) << 16);
        o.w = f2bf(b.z) | (f2bf(b.w) << 16);
        reinterpret_cast<uint4*>(xbf)[i] = o;
    }

    // B-frag for tile (nt,ks): lane l holds B[k=ks*32+(l>>4)*8+j][col=nt*16+(l&15)]
    if (i < 768) {                         // W1: 4 nt x 3 ks x 64 lanes
        const int ti = i >> 6, lane = i & 63;
        const int nt = ti / 3, ks = ti % 3;
        const int col = nt * 16 + (lane & 15);
        const int k0  = ks * 32 + ((lane >> 4) << 3);
        unsigned o[4];
#pragma unroll
        for (int p = 0; p < 4; ++p)
            o[p] = f2bf(W1[(k0 + 2 * p) * HID + col]) |
                   (f2bf(W1[(k0 + 2 * p + 1) * HID + col]) << 16);
        reinterpret_cast<uint4*>(w1s)[i] = make_uint4(o[0], o[1], o[2], o[3]);
    } else if (i < 1024) {                 // W2: 2 nt x 2 ks x 64 lanes
        const int tt = i - 768;
        const int ti = tt >> 6, lane = tt & 63;
        const int nt = ti >> 1, ks = ti & 1;
        const int col = nt * 16 + (lane & 15);
        const int k0  = ks * 32 + ((lane >> 4) << 3);
        unsigned o[4];
#pragma unroll
        for (int p = 0; p < 4; ++p)
            o[p] = f2bf(W2[(k0 + 2 * p) * OUTD + col]) |
                   (f2bf(W2[(k0 + 2 * p + 1) * OUTD + col]) << 16);
        reinterpret_cast<uint4*>(w2s)[tt] = make_uint4(o[0], o[1], o[2], o[3]);
    }
}

// ---- hierarchical exclusive scan over degree[N] ----
// scan1: per-block (1024 elems) exclusive scan -> start[], block total -> bsums[b]
__global__ __launch_bounds__(256) void scan1(
    const unsigned* __restrict__ degree, unsigned* __restrict__ start,
    unsigned* __restrict__ bsums, int n)
{
    __shared__ unsigned ts[256];
    const int t  = threadIdx.x;
    const int i0 = blockIdx.x * SCAN_CHUNK + t * 4;

    unsigned d0 = 0, d1 = 0, d2 = 0, d3 = 0;
    if (i0 + 3 < n) {
        uint4 d = *reinterpret_cast<const uint4*>(degree + i0);
        d0 = d.x; d1 = d.y; d2 = d.z; d3 = d.w;
    } else {
        if (i0     < n) d0 = degree[i0];
        if (i0 + 1 < n) d1 = degree[i0 + 1];
        if (i0 + 2 < n) d2 = degree[i0 + 2];
        if (i0 + 3 < n) d3 = degree[i0 + 3];
    }
    ts[t] = d0 + d1 + d2 + d3;
    __syncthreads();
#pragma unroll
    for (int off = 1; off < 256; off <<= 1) {
        unsigned val = (t >= off) ? ts[t - off] : 0u;
        __syncthreads();
        ts[t] += val;
        __syncthreads();
    }
    const unsigned excl = (t == 0) ? 0u : ts[t - 1];
    const unsigned e0 = excl, e1 = e0 + d0, e2 = e1 + d1, e3 = e2 + d2;
    if (i0 + 3 < n) {
        *reinterpret_cast<uint4*>(start + i0) = make_uint4(e0, e1, e2, e3);
    } else {
        if (i0     < n) start[i0]     = e0;
        if (i0 + 1 < n) start[i0 + 1] = e1;
        if (i0 + 2 < n) start[i0 + 2] = e2;
        if (i0 + 3 < n) start[i0 + 3] = e3;
    }
    if (t == 255) bsums[blockIdx.x] = ts[255];
}

// scan2: single block scans bsums[nb] (nb <= 256) in place; total -> bsums[nb]
__global__ __launch_bounds__(256) void scan2(unsigned* __restrict__ bsums, int nb)
{
    __shared__ unsigned ts[256];
    const int t = threadIdx.x;
    ts[t] = (t < nb) ? bsums[t] : 0u;
    __syncthreads();
#pragma unroll
    for (int off = 1; off < 256; off <<= 1) {
        unsigned val = (t >= off) ? ts[t - off] : 0u;
        __syncthreads();
        ts[t] += val;
        __syncthreads();
    }
    if (t < nb)  bsums[t]  = (t == 0) ? 0u : ts[t - 1];
    if (t == nb) bsums[nb] = ts[nb - 1];     // grand total (nb < 256)
}

// scan3: add block offsets; write start (incl. start[n]=E) and cursor
__global__ __launch_bounds__(256) void scan3(
    unsigned* __restrict__ start, unsigned* __restrict__ cursor,
    const unsigned* __restrict__ bsums, int n)
{
    const int i = blockIdx.x * 256 + threadIdx.x;
    if (i < n) {
        const unsigned v = start[i] + bsums[i / SCAN_CHUNK];
        start[i]  = v;
        cursor[i] = v;
    } else if (i == n) {
        start[n] = bsums[(n + SCAN_CHUNK - 1) / SCAN_CHUNK];
    }
}

__global__ __launch_bounds__(256) void scatter_csr(
    const int* __restrict__ ei, unsigned* __restrict__ cursor,
    unsigned* __restrict__ csr, int n_edges)
{
    int e = blockIdx.x * 256 + threadIdx.x;
    if (e >= n_edges) return;
    const int col = ei[n_edges + e];
    const unsigned pos = atomicAdd(&cursor[col], 1u);
    csr[pos] = (unsigned)e;
}

// ---- per-128-edge-block MFMA MLP ----
__global__ __launch_bounds__(256) void edge_mlp_mfma(
    const unsigned* __restrict__ xbf,   // [N][16] u32 = [N][32] bf16
    const int*      __restrict__ ei,
    const float*    __restrict__ ea,
    const unsigned* __restrict__ w1s,   // [12][64] x 16B frags
    const unsigned* __restrict__ w2s,   // [4][64] x 16B frags
    const float*    __restrict__ b1,
    const float*    __restrict__ b2,
    unsigned*       __restrict__ v,     // [E][16] u32 = [E][32] bf16
    int n_edges)
{
    __shared__ alignas(16) unsigned short Albs[BM * ASTR];
    __shared__ alignas(16) unsigned short Hlds[BM * HSTR];

    const int t    = threadIdx.x;
    const int lane = t & 63;
    const int wave = t >> 6;
    const int base = blockIdx.x * BM;

    // stage A[:, 0:64]: gather 2 endpoint rows per edge (thread = (edge, side))
    {
        const int m    = t & 127;
        const int side = t >> 7;
        int e = base + m; if (e >= n_edges) e = n_edges - 1;
        const int id = ei[side * n_edges + e];
        const uint4* src = reinterpret_cast<const uint4*>(xbf + (size_t)id * 16);
#pragma unroll
        for (int q = 0; q < 4; ++q)
            *reinterpret_cast<uint4*>(&Albs[m * ASTR + side * 32 + q * 8]) = src[q];
    }
    // stage A[:, 64:96]: ea f32->bf16, coalesced non-temporal stream
    {
#pragma unroll
        for (int i = 0; i < 4; ++i) {
            const int f = t + i * 256;
            const int m = f >> 3;
            const int c = (f & 7) * 4;
            int e = base + m; if (e >= n_edges) e = n_edges - 1;
            const floatx4 d = __builtin_nontemporal_load(
                reinterpret_cast<const floatx4*>(ea + (size_t)e * 32 + c));
            uint2 pk;
            pk.x = f2bf(d.x) | (f2bf(d.y) << 16);
            pk.y = f2bf(d.z) | (f2bf(d.w) << 16);
            *reinterpret_cast<uint2*>(&Albs[m * ASTR + 64 + c]) = pk;
        }
    }

    short8 w1f[12];
#pragma unroll
    for (int ti = 0; ti < 12; ++ti)
        w1f[ti] = *reinterpret_cast<const short8*>(w1s + (size_t)(ti * 64 + lane) * 4);
    float bb1[4];
#pragma unroll
    for (int nt = 0; nt < 4; ++nt) bb1[nt] = b1[nt * 16 + (lane & 15)];

    __syncthreads();

    // layer 1: [128x96] @ [96x64]
    f32x4 acc1[2][4];
#pragma unroll
    for (int mi = 0; mi < 2; ++mi)
#pragma unroll
        for (int nt = 0; nt < 4; ++nt) acc1[mi][nt] = (f32x4){0.f, 0.f, 0.f, 0.f};

#pragma unroll
    for (int ks = 0; ks < 3; ++ks) {
#pragma unroll
        for (int mi = 0; mi < 2; ++mi) {
            const int mt = wave * 2 + mi;
            short8 afrag = *reinterpret_cast<const short8*>(
                &Albs[(mt * 16 + (lane & 15)) * ASTR + ks * 32 + ((lane >> 4) << 3)]);
#pragma unroll
            for (int nt = 0; nt < 4; ++nt)
                acc1[mi][nt] = __builtin_amdgcn_mfma_f32_16x16x32_bf16(
                    afrag, w1f[nt * 3 + ks], acc1[mi][nt], 0, 0, 0);
        }
    }

    // bias + ReLU -> H (bf16, LDS). C layout: col=lane&15, row=(lane>>4)*4+r.
#pragma unroll
    for (int mi = 0; mi < 2; ++mi) {
        const int mt = wave * 2 + mi;
#pragma unroll
        for (int nt = 0; nt < 4; ++nt)
#pragma unroll
            for (int r = 0; r < 4; ++r) {
                const float h = fmaxf(acc1[mi][nt][r] + bb1[nt], 0.0f);
                Hlds[(mt * 16 + ((lane >> 4) << 2) + r) * HSTR + nt * 16 + (lane & 15)] =
                    (unsigned short)f2bf(h);
            }
    }

    short8 w2f[4];
#pragma unroll
    for (int ti = 0; ti < 4; ++ti)
        w2f[ti] = *reinterpret_cast<const short8*>(w2s + (size_t)(ti * 64 + lane) * 4);
    float bb2[2];
#pragma unroll
    for (int nt = 0; nt < 2; ++nt) bb2[nt] = b2[nt * 16 + (lane & 15)];

    __syncthreads();

    // layer 2: [128x64] @ [64x32]
    f32x4 acc2[2][2];
#pragma unroll
    for (int mi = 0; mi < 2; ++mi)
#pragma unroll
        for (int nt = 0; nt < 2; ++nt) acc2[mi][nt] = (f32x4){0.f, 0.f, 0.f, 0.f};

#pragma unroll
    for (int ks = 0; ks < 2; ++ks) {
#pragma unroll
        for (int mi = 0; mi < 2; ++mi) {
            const int mt = wave * 2 + mi;
            short8 hfrag = *reinterpret_cast<const short8*>(
                &Hlds[(mt * 16 + (lane & 15)) * HSTR + ks * 32 + ((lane >> 4) << 3)]);
#pragma unroll
            for (int nt = 0; nt < 2; ++nt)
                acc2[mi][nt] = __builtin_amdgcn_mfma_f32_16x16x32_bf16(
                    hfrag, w2f[nt * 2 + ks], acc2[mi][nt], 0, 0, 0);
        }
    }

    // bias, pack V (bf16) via LDS, coalesced store
    unsigned short* Vlds = Albs;
#pragma unroll
    for (int mi = 0; mi < 2; ++mi) {
        const int mt = wave * 2 + mi;
#pragma unroll
        for (int nt = 0; nt < 2; ++nt)
#pragma unroll
            for (int r = 0; r < 4; ++r) {
                const float val = acc2[mi][nt][r] + bb2[nt];
                Vlds[(mt * 16 + ((lane >> 4) << 2) + r) * VSTR + nt * 16 + (lane & 15)] =
                    (unsigned short)f2bf(val);
            }
    }
    __syncthreads();

#pragma unroll
    for (int i = 0; i < 2; ++i) {
        const int f = t + i * 256;
        const int m = f >> 2;
        const int q = f & 3;
        const int e = base + m;
        if (e < n_edges) {
            u32x4 val = *reinterpret_cast<const u32x4*>(&Vlds[m * VSTR + q * 8]);
            __builtin_nontemporal_store(val, reinterpret_cast<u32x4*>(v + (size_t)e * 16) + q);
        }
    }
}

__global__ __launch_bounds__(256) void node_gather_max(
    const float*    __restrict__ x,
    const unsigned* __restrict__ start,  // [N+1]
    const unsigned* __restrict__ csr,    // [E]
    const unsigned short* __restrict__ v,
    float* __restrict__ out, int n_nodes)
{
    const int t = blockIdx.x * 256 + threadIdx.x;
    const int n = t >> 5;          // 32 lanes per node
    const int j = t & 31;
    if (n >= n_nodes) return;

    const unsigned s0 = start[n];
    const int deg = (int)(start[n + 1] - s0);

    const float NEG = __uint_as_float(0xff800000u);
    float m0 = x[(size_t)n * XD + j];   // residual (XD==OUTD)
    float m1 = NEG, m2 = NEG, m3 = NEG;

    int k = 0;
    while (k < deg) {
        const int cnt = min(deg - k, 32);
        unsigned eid = 0;
        if (j < cnt) eid = csr[s0 + k + j];
        int kk = 0;
        for (; kk + 4 <= cnt; kk += 4) {
            const unsigned e0 = __shfl(eid, kk,     32);
            const unsigned e1 = __shfl(eid, kk + 1, 32);
            const unsigned e2 = __shfl(eid, kk + 2, 32);
            const unsigned e3 = __shfl(eid, kk + 3, 32);
            const unsigned u0 = v[(size_t)e0 * OUTD + j];
            const unsigned u1 = v[(size_t)e1 * OUTD + j];
            const unsigned u2 = v[(size_t)e2 * OUTD + j];
            const unsigned u3 = v[(size_t)e3 * OUTD + j];
            m0 = fmaxf(m0, __uint_as_float(u0 << 16));
            m1 = fmaxf(m1, __uint_as_float(u1 << 16));
            m2 = fmaxf(m2, __uint_as_float(u2 << 16));
            m3 = fmaxf(m3, __uint_as_float(u3 << 16));
        }
        for (; kk < cnt; ++kk) {
            const unsigned e0 = __shfl(eid, kk, 32);
            m0 = fmaxf(m0, __uint_as_float((unsigned)v[(size_t)e0 * OUTD + j] << 16));
        }
        k += cnt;
    }
    out[(size_t)n * OUTD + j] = fmaxf(fmaxf(m0, m1), fmaxf(m2, m3));
}

extern "C" void kernel_launch(void* const* d_in, const int* in_sizes, int n_in,
                              void* d_out, int out_size, void* d_ws, size_t ws_size,
                              hipStream_t stream)
{
    const float* x  = (const float*)d_in[0];
    const int*   ei = (const int*)  d_in[1];
    const float* ea = (const float*)d_in[2];
    const float* W1 = (const float*)d_in[3];
    const float* b1 = (const float*)d_in[4];
    const float* W2 = (const float*)d_in[5];
    const float* b2 = (const float*)d_in[6];
    float* out = (float*)d_out;

    const int n_nodes = in_sizes[0] / XD;
    const int n_edges = in_sizes[2] / 32;
    const int nb_scan = (n_nodes + SCAN_CHUNK - 1) / SCAN_CHUNK;   // blocks in scan1 (<=256)

    // ws: degree[N] | cursor[N] | start[N+1] | bsums[nb+1] | csr[E] | v[E*16 u32] | xbf | w1s | w2s
    size_t off = 0;
    unsigned* degree = (unsigned*)((char*)d_ws + off); off += (size_t)n_nodes * 4;
    unsigned* cursor = (unsigned*)((char*)d_ws + off); off += (size_t)n_nodes * 4;
    unsigned* startp = (unsigned*)((char*)d_ws + off); off += (size_t)(n_nodes + 1) * 4;
    unsigned* bsums  = (unsigned*)((char*)d_ws + off); off += (size_t)(nb_scan + 1) * 4;
    off = (off + 15) & ~(size_t)15;
    unsigned* csr    = (unsigned*)((char*)d_ws + off); off += (size_t)n_edges * 4;
    off = (off + 15) & ~(size_t)15;
    unsigned* v      = (unsigned*)((char*)d_ws + off); off += (size_t)n_edges * 16 * 4;
    unsigned* xbf    = (unsigned*)((char*)d_ws + off); off += (size_t)n_nodes * 16 * 4;
    unsigned* w1s    = (unsigned*)((char*)d_ws + off); off += 768 * 16;
    unsigned* w2s    = (unsigned*)((char*)d_ws + off);

    const int total8 = n_nodes * XD / 8;

    zero_u32<<<(n_nodes + 255) / 256, 256, 0, stream>>>(degree, n_nodes);
    prep_count<<<(n_edges + 255) / 256, 256, 0, stream>>>(
        x, xbf, ei, degree, W1, W2, w1s, w2s, n_edges, total8);
    scan1<<<nb_scan, 256, 0, stream>>>(degree, startp, bsums, n_nodes);
    scan2<<<1, 256, 0, stream>>>(bsums, nb_scan);
    scan3<<<(n_nodes + 256) / 256, 256, 0, stream>>>(startp, cursor, bsums, n_nodes);
    scatter_csr<<<(n_edges + 255) / 256, 256, 0, stream>>>(ei, cursor, csr, n_edges);
    edge_mlp_mfma<<<(n_edges + BM - 1) / BM, 256, 0, stream>>>(
        xbf, ei, ea, w1s, w2s, b1, b2, v, n_edges);
    node_gather_max<<<(n_nodes * 32 + 255) / 256, 256, 0, stream>>>(
        x, startp, csr, (const unsigned short*)v, out, n_nodes);
}

// Round 8
// 158.494 us; speedup vs baseline: 1.7487x; 1.1095x over previous
//
#include <hip/hip_runtime.h>

// PathGNNLayers: per-edge MLP + scatter-max GNN layer.
//   x:[N,32] f32, edge_index:[2,E] int32, edge_attr:[E,32] f32
//   W1:[96,64], b1:[64], W2:[64,32], b2:[32]
//   out[n] = max( x[n, -32:], max_{e: col[e]==n} MLP(x[row_e], x[col_e], ea[e]) )
//
// R8: CSR-ordered fused MLP+aggregation. scatter stores {e,row,col} per CSR
// position; the MFMA kernel processes 128 CSR-consecutive edges, so rows of
// one node are adjacent (cols non-decreasing) and a segmented LDS max +
// sign-split atomics replaces the 51MB v round-trip and the gather kernel.
// 6 launches: init, prep_count, scan1, scan3(+bsum reduce), scatter_rc, fused.

constexpr int XD   = 32;
constexpr int HID  = 64;
constexpr int OUTD = 32;
constexpr int BM   = 128;   // edges per block (MFMA kernel)
constexpr int ASTR = 104;   // A LDS stride in bf16 units
constexpr int HSTR = 72;    // H LDS stride in bf16 units
constexpr int VSTR = 40;    // V staging stride in bf16 units
constexpr int SCAN_CHUNK = 1024;  // elements per scan1 block (256 thr x 4)

typedef __attribute__((ext_vector_type(8)))  short    short8;
typedef __attribute__((ext_vector_type(4)))  float    f32x4;
typedef __attribute__((ext_vector_type(4)))  float    floatx4;

static __device__ __forceinline__ unsigned f2bf(float f) {
    union { float f; unsigned u; } x; x.f = f;
    unsigned r = x.u + 0x7fff + ((x.u >> 16) & 1);   // RNE; finite inputs
    return r >> 16;
}

// float atomic-max via monotone integer encoding (exact, order-independent)
static __device__ __forceinline__ void atomax_f32(float* addr, float v) {
    if (v >= 0.0f) atomicMax(reinterpret_cast<int*>(addr), __float_as_int(v));
    else           atomicMin(reinterpret_cast<unsigned*>(addr), __float_as_uint(v));
}

// ---- init: out = x (residual + empty-segment floor), degree = 0 ----
__global__ __launch_bounds__(256) void init_out_deg(
    const float* __restrict__ x, float* __restrict__ out,
    unsigned* __restrict__ degree, int n_nodes, int total4)
{
    const int i = blockIdx.x * 256 + threadIdx.x;
    if (i < total4)
        reinterpret_cast<float4*>(out)[i] = reinterpret_cast<const float4*>(x)[i];
    if (i < n_nodes) degree[i] = 0u;
}

// ---- prep: degree count + x->bf16 + W1/W2 -> bf16 MFMA B-fragment order ----
__global__ __launch_bounds__(256) void prep_count(
    const float* __restrict__ x, unsigned* __restrict__ xbf,
    const int* __restrict__ ei,  unsigned* __restrict__ degree,
    const float* __restrict__ W1, const float* __restrict__ W2,
    unsigned* __restrict__ w1s, unsigned* __restrict__ w2s,
    int n_edges, int total8)
{
    const int i = blockIdx.x * 256 + threadIdx.x;

    if (i < n_edges) atomicAdd(&degree[ei[n_edges + i]], 1u);

    if (i < total8) {                      // x (f32) -> xbf (bf16), 8 floats/thread
        const float4* src = reinterpret_cast<const float4*>(x) + (size_t)i * 2;
        float4 a = src[0], b = src[1];
        uint4 o;
        o.x = f2bf(a.x) | (f2bf(a.y) << 16);
        o.y = f2bf(a.z) | (f2bf(a.w) << 16);
        o.z = f2bf(b.x) | (f2bf(b.y) << 16);
        o.w = f2bf(b.z) | (f2bf(b.w) << 16);
        reinterpret_cast<uint4*>(xbf)[i] = o;
    }

    // B-frag for tile (nt,ks): lane l holds B[k=ks*32+(l>>4)*8+j][col=nt*16+(l&15)]
    if (i < 768) {                         // W1: 4 nt x 3 ks x 64 lanes
        const int ti = i >> 6, lane = i & 63;
        const int nt = ti / 3, ks = ti % 3;
        const int col = nt * 16 + (lane & 15);
        const int k0  = ks * 32 + ((lane >> 4) << 3);
        unsigned o[4];
#pragma unroll
        for (int p = 0; p < 4; ++p)
            o[p] = f2bf(W1[(k0 + 2 * p) * HID + col]) |
                   (f2bf(W1[(k0 + 2 * p + 1) * HID + col]) << 16);
        reinterpret_cast<uint4*>(w1s)[i] = make_uint4(o[0], o[1], o[2], o[3]);
    } else if (i < 1024) {                 // W2: 2 nt x 2 ks x 64 lanes
        const int tt = i - 768;
        const int ti = tt >> 6, lane = tt & 63;
        const int nt = ti >> 1, ks = ti & 1;
        const int col = nt * 16 + (lane & 15);
        const int k0  = ks * 32 + ((lane >> 4) << 3);
        unsigned o[4];
#pragma unroll
        for (int p = 0; p < 4; ++p)
            o[p] = f2bf(W2[(k0 + 2 * p) * OUTD + col]) |
                   (f2bf(W2[(k0 + 2 * p + 1) * OUTD + col]) << 16);
        reinterpret_cast<uint4*>(w2s)[tt] = make_uint4(o[0], o[1], o[2], o[3]);
    }
}

// ---- hierarchical exclusive scan over degree[N] ----
__global__ __launch_bounds__(256) void scan1(
    const unsigned* __restrict__ degree, unsigned* __restrict__ start,
    unsigned* __restrict__ bsums, int n)
{
    __shared__ unsigned ts[256];
    const int t  = threadIdx.x;
    const int i0 = blockIdx.x * SCAN_CHUNK + t * 4;

    unsigned d0 = 0, d1 = 0, d2 = 0, d3 = 0;
    if (i0 + 3 < n) {
        uint4 d = *reinterpret_cast<const uint4*>(degree + i0);
        d0 = d.x; d1 = d.y; d2 = d.z; d3 = d.w;
    } else {
        if (i0     < n) d0 = degree[i0];
        if (i0 + 1 < n) d1 = degree[i0 + 1];
        if (i0 + 2 < n) d2 = degree[i0 + 2];
        if (i0 + 3 < n) d3 = degree[i0 + 3];
    }
    ts[t] = d0 + d1 + d2 + d3;
    __syncthreads();
#pragma unroll
    for (int off = 1; off < 256; off <<= 1) {
        unsigned val = (t >= off) ? ts[t - off] : 0u;
        __syncthreads();
        ts[t] += val;
        __syncthreads();
    }
    const unsigned excl = (t == 0) ? 0u : ts[t - 1];
    const unsigned e0 = excl, e1 = e0 + d0, e2 = e1 + d1, e3 = e2 + d2;
    if (i0 + 3 < n) {
        *reinterpret_cast<uint4*>(start + i0) = make_uint4(e0, e1, e2, e3);
    } else {
        if (i0     < n) start[i0]     = e0;
        if (i0 + 1 < n) start[i0 + 1] = e1;
        if (i0 + 2 < n) start[i0 + 2] = e2;
        if (i0 + 3 < n) start[i0 + 3] = e3;
    }
    if (t == 255) bsums[blockIdx.x] = ts[255];
}

// scan3: per-block wave-reduce of bsums prefix (nb <= ~256), apply offsets,
// write start (incl. start[n]=E) and cursor.
__global__ __launch_bounds__(256) void scan3(
    unsigned* __restrict__ start, unsigned* __restrict__ cursor,
    const unsigned* __restrict__ bsums, int n, int nb)
{
    __shared__ unsigned spre[2];
    const int t = threadIdx.x;
    const int c = (blockIdx.x * 256) / SCAN_CHUNK;   // block spans one chunk

    if (t < 64) {
        unsigned vc = 0, va = 0;
        for (int b = t; b < nb; b += 64) {
            const unsigned s = bsums[b];
            va += s;
            if (b < c) vc += s;
        }
#pragma unroll
        for (int o = 32; o; o >>= 1) {
            vc += __shfl_down(vc, o, 64);
            va += __shfl_down(va, o, 64);
        }
        if (t == 0) { spre[0] = vc; spre[1] = va; }
    }
    __syncthreads();

    const int i = blockIdx.x * 256 + t;
    if (i < n) {
        const unsigned v = start[i] + spre[0];
        start[i]  = v;
        cursor[i] = v;
    } else if (i == n) {
        start[n] = spre[1];
    }
}

// scatter: one 16B store per edge -> rc4[pos] = {e, row, col, 0}
__global__ __launch_bounds__(256) void scatter_rc(
    const int* __restrict__ ei, unsigned* __restrict__ cursor,
    uint4* __restrict__ rc4, int n_edges)
{
    int e = blockIdx.x * 256 + threadIdx.x;
    if (e >= n_edges) return;
    const int row = ei[e];
    const int col = ei[n_edges + e];
    const unsigned pos = atomicAdd(&cursor[col], 1u);
    rc4[pos] = make_uint4((unsigned)e, (unsigned)row, (unsigned)col, 0u);
}

// ---- fused: per-128-CSR-position MFMA MLP + segmented scatter-max ----
__global__ __launch_bounds__(256) void edge_mlp_fused(
    const unsigned* __restrict__ xbf,   // [N][16] u32 = [N][32] bf16
    const uint4*    __restrict__ rc4,   // [E] {e,row,col,0} in CSR order
    const float*    __restrict__ ea,
    const unsigned* __restrict__ w1s,   // [12][64] x 16B frags
    const unsigned* __restrict__ w2s,   // [4][64] x 16B frags
    const float*    __restrict__ b1,
    const float*    __restrict__ b2,
    float*          __restrict__ out,   // [N][32] f32, pre-init to x
    int n_edges)
{
    __shared__ alignas(16) unsigned short Albs[BM * ASTR];
    __shared__ alignas(16) unsigned short Hlds[BM * HSTR];
    __shared__ unsigned rcsE[BM];
    __shared__ unsigned rcsR[BM];
    __shared__ unsigned rcsC[BM];

    const int t    = threadIdx.x;
    const int lane = t & 63;
    const int wave = t >> 6;
    const int base = blockIdx.x * BM;

    // phase 0: load CSR records for this tile (padded rows clamp to last edge;
    // duplicates are harmless because max is idempotent)
    if (t < BM) {
        int p = base + t; if (p >= n_edges) p = n_edges - 1;
        const uint4 q = rc4[p];
        rcsE[t] = q.x; rcsR[t] = q.y; rcsC[t] = q.z;
    }
    __syncthreads();

    // stage A[:, 0:64]: gather endpoint rows (thread = (edge m, side))
    {
        const int m    = t & 127;
        const int side = t >> 7;                    // 0 -> x[row], 1 -> x[col]
        const unsigned id = side ? rcsC[m] : rcsR[m];
        const uint4* src = reinterpret_cast<const uint4*>(xbf + (size_t)id * 16);
#pragma unroll
        for (int q = 0; q < 4; ++q)
            *reinterpret_cast<uint4*>(&Albs[m * ASTR + side * 32 + q * 8]) = src[q];
    }
    // stage A[:, 64:96]: ea rows gathered by edge id, f32->bf16
    {
#pragma unroll
        for (int i = 0; i < 4; ++i) {
            const int f = t + i * 256;
            const int m = f >> 3;
            const int c = (f & 7) * 4;
            const unsigned e = rcsE[m];
            const floatx4 d = __builtin_nontemporal_load(
                reinterpret_cast<const floatx4*>(ea + (size_t)e * 32 + c));
            uint2 pk;
            pk.x = f2bf(d.x) | (f2bf(d.y) << 16);
            pk.y = f2bf(d.z) | (f2bf(d.w) << 16);
            *reinterpret_cast<uint2*>(&Albs[m * ASTR + 64 + c]) = pk;
        }
    }

    short8 w1f[12];
#pragma unroll
    for (int ti = 0; ti < 12; ++ti)
        w1f[ti] = *reinterpret_cast<const short8*>(w1s + (size_t)(ti * 64 + lane) * 4);
    float bb1[4];
#pragma unroll
    for (int nt = 0; nt < 4; ++nt) bb1[nt] = b1[nt * 16 + (lane & 15)];

    __syncthreads();

    // layer 1: [128x96] @ [96x64]
    f32x4 acc1[2][4];
#pragma unroll
    for (int mi = 0; mi < 2; ++mi)
#pragma unroll
        for (int nt = 0; nt < 4; ++nt) acc1[mi][nt] = (f32x4){0.f, 0.f, 0.f, 0.f};

#pragma unroll
    for (int ks = 0; ks < 3; ++ks) {
#pragma unroll
        for (int mi = 0; mi < 2; ++mi) {
            const int mt = wave * 2 + mi;
            short8 afrag = *reinterpret_cast<const short8*>(
                &Albs[(mt * 16 + (lane & 15)) * ASTR + ks * 32 + ((lane >> 4) << 3)]);
#pragma unroll
            for (int nt = 0; nt < 4; ++nt)
                acc1[mi][nt] = __builtin_amdgcn_mfma_f32_16x16x32_bf16(
                    afrag, w1f[nt * 3 + ks], acc1[mi][nt], 0, 0, 0);
        }
    }

    // bias + ReLU -> H (bf16, LDS). C layout: col=lane&15, row=(lane>>4)*4+r.
#pragma unroll
    for (int mi = 0; mi < 2; ++mi) {
        const int mt = wave * 2 + mi;
#pragma unroll
        for (int nt = 0; nt < 4; ++nt)
#pragma unroll
            for (int r = 0; r < 4; ++r) {
                const float h = fmaxf(acc1[mi][nt][r] + bb1[nt], 0.0f);
                Hlds[(mt * 16 + ((lane >> 4) << 2) + r) * HSTR + nt * 16 + (lane & 15)] =
                    (unsigned short)f2bf(h);
            }
    }

    short8 w2f[4];
#pragma unroll
    for (int ti = 0; ti < 4; ++ti)
        w2f[ti] = *reinterpret_cast<const short8*>(w2s + (size_t)(ti * 64 + lane) * 4);
    float bb2[2];
#pragma unroll
    for (int nt = 0; nt < 2; ++nt) bb2[nt] = b2[nt * 16 + (lane & 15)];

    __syncthreads();

    // layer 2: [128x64] @ [64x32]
    f32x4 acc2[2][2];
#pragma unroll
    for (int mi = 0; mi < 2; ++mi)
#pragma unroll
        for (int nt = 0; nt < 2; ++nt) acc2[mi][nt] = (f32x4){0.f, 0.f, 0.f, 0.f};

#pragma unroll
    for (int ks = 0; ks < 2; ++ks) {
#pragma unroll
        for (int mi = 0; mi < 2; ++mi) {
            const int mt = wave * 2 + mi;
            short8 hfrag = *reinterpret_cast<const short8*>(
                &Hlds[(mt * 16 + (lane & 15)) * HSTR + ks * 32 + ((lane >> 4) << 3)]);
#pragma unroll
            for (int nt = 0; nt < 2; ++nt)
                acc2[mi][nt] = __builtin_amdgcn_mfma_f32_16x16x32_bf16(
                    hfrag, w2f[nt * 2 + ks], acc2[mi][nt], 0, 0, 0);
        }
    }

    // bias, V (bf16) -> LDS (reuse Albs; last Albs read was before prior barrier)
    unsigned short* Vlds = Albs;
#pragma unroll
    for (int mi = 0; mi < 2; ++mi) {
        const int mt = wave * 2 + mi;
#pragma unroll
        for (int nt = 0; nt < 2; ++nt)
#pragma unroll
            for (int r = 0; r < 4; ++r) {
                const float val = acc2[mi][nt][r] + bb2[nt];
                Vlds[(mt * 16 + ((lane >> 4) << 2) + r) * VSTR + nt * 16 + (lane & 15)] =
                    (unsigned short)f2bf(val);
            }
    }
    __syncthreads();

    // segmented max: 8 groups x 32 lanes; group g walks rows [g*16, g*16+16).
    // CSR order => node ids (rcsC) are non-decreasing within the tile.
    {
        const int g  = t >> 5;
        const int j  = t & 31;
        const int r0 = g * 16;

        unsigned ncur = rcsC[r0];
        float mv = __uint_as_float((unsigned)Vlds[r0 * VSTR + j] << 16);
#pragma unroll
        for (int r = 1; r < 16; ++r) {
            const unsigned nd = rcsC[r0 + r];
            const float val = __uint_as_float((unsigned)Vlds[(r0 + r) * VSTR + j] << 16);
            if (nd != ncur) {
                atomax_f32(out + (size_t)ncur * OUTD + j, mv);
                ncur = nd;
                mv = val;
            } else {
                mv = fmaxf(mv, val);
            }
        }
        atomax_f32(out + (size_t)ncur * OUTD + j, mv);
    }
}

extern "C" void kernel_launch(void* const* d_in, const int* in_sizes, int n_in,
                              void* d_out, int out_size, void* d_ws, size_t ws_size,
                              hipStream_t stream)
{
    const float* x  = (const float*)d_in[0];
    const int*   ei = (const int*)  d_in[1];
    const float* ea = (const float*)d_in[2];
    const float* W1 = (const float*)d_in[3];
    const float* b1 = (const float*)d_in[4];
    const float* W2 = (const float*)d_in[5];
    const float* b2 = (const float*)d_in[6];
    float* out = (float*)d_out;

    const int n_nodes = in_sizes[0] / XD;
    const int n_edges = in_sizes[2] / 32;
    const int nb_scan = (n_nodes + SCAN_CHUNK - 1) / SCAN_CHUNK;

    // ws: degree[N] | cursor[N] | start[N+1] | bsums[nb+1] | rc4[E] uint4 | xbf | w1s | w2s
    size_t off = 0;
    unsigned* degree = (unsigned*)((char*)d_ws + off); off += (size_t)n_nodes * 4;
    unsigned* cursor = (unsigned*)((char*)d_ws + off); off += (size_t)n_nodes * 4;
    unsigned* startp = (unsigned*)((char*)d_ws + off); off += (size_t)(n_nodes + 1) * 4;
    unsigned* bsums  = (unsigned*)((char*)d_ws + off); off += (size_t)(nb_scan + 1) * 4;
    off = (off + 15) & ~(size_t)15;
    uint4*    rc4    = (uint4*)   ((char*)d_ws + off); off += (size_t)n_edges * 16;
    unsigned* xbf    = (unsigned*)((char*)d_ws + off); off += (size_t)n_nodes * 16 * 4;
    unsigned* w1s    = (unsigned*)((char*)d_ws + off); off += 768 * 16;
    unsigned* w2s    = (unsigned*)((char*)d_ws + off);

    const int total8 = n_nodes * XD / 8;
    const int total4 = n_nodes * OUTD / 4;

    init_out_deg<<<(total4 + 255) / 256, 256, 0, stream>>>(x, out, degree, n_nodes, total4);
    prep_count<<<(n_edges + 255) / 256, 256, 0, stream>>>(
        x, xbf, ei, degree, W1, W2, w1s, w2s, n_edges, total8);
    scan1<<<nb_scan, 256, 0, stream>>>(degree, startp, bsums, n_nodes);
    scan3<<<(n_nodes + 256) / 256, 256, 0, stream>>>(startp, cursor, bsums, n_nodes, nb_scan);
    scatter_rc<<<(n_edges + 255) / 256, 256, 0, stream>>>(ei, cursor, rc4, n_edges);
    edge_mlp_fused<<<(n_edges + BM - 1) / BM, 256, 0, stream>>>(
        xbf, rc4, ea, w1s, w2s, b1, b2, out, n_edges);
}